// Round 1
// baseline (951.185 us; speedup 1.0000x reference)
//
#include <hip/hip_runtime.h>

// Problem constants
// DIM=256 H=8 HD=32 W=64 N=8192 nw=128
// xyz: T=40, 3 ch, off=20, hi=39 ; rgb: T=32, 3 ch, off=16, hi=31
// combined table rows: xyz R=120 (stride 121), rgb R=96 (stride 97)
// table element ((c*T+t)*8+h)*32 + d  ==  (r*256) + h*32 + d  with r=c*T+t

// ---------------------------------------------------------------------------
// QKV GEMM: qkv[m, c] = feats[m,:] . qkv_w[c,:] + qkv_b[c]; scatter to q/k/v
// layout [nw][H][W][HD], q pre-scaled by 32^-0.5. BM=128 BN=64 BK=16.
// ---------------------------------------------------------------------------
__global__ __launch_bounds__(256) void k_qkv(
    const float* __restrict__ A, const float* __restrict__ Wt,
    const float* __restrict__ bias,
    float* __restrict__ qb, float* __restrict__ kb, float* __restrict__ vb)
{
    __shared__ float a_t[16][132];   // [k][m]
    __shared__ float b_t[16][68];    // [k][n]
    const int tid = threadIdx.x;
    const int m0 = blockIdx.y * 128;
    const int n0 = blockIdx.x * 64;
    const int tx = tid & 15;         // n dir (x4)
    const int ty = tid >> 4;         // m dir (x8)
    float acc[8][4];
#pragma unroll
    for (int i = 0; i < 8; ++i)
#pragma unroll
        for (int j = 0; j < 4; ++j) acc[i][j] = 0.f;

    for (int k0 = 0; k0 < 256; k0 += 16) {
#pragma unroll
        for (int l = 0; l < 2; ++l) {
            int e = tid + l * 256;   // 0..511
            int r = e >> 2;          // 0..127
            int kq = e & 3;
            float4 v = *(const float4*)(A + (size_t)(m0 + r) * 256 + k0 + kq * 4);
            a_t[kq*4+0][r] = v.x; a_t[kq*4+1][r] = v.y;
            a_t[kq*4+2][r] = v.z; a_t[kq*4+3][r] = v.w;
        }
        {
            int r = tid >> 2;        // 0..63
            int kq = tid & 3;
            float4 v = *(const float4*)(Wt + (size_t)(n0 + r) * 256 + k0 + kq * 4);
            b_t[kq*4+0][r] = v.x; b_t[kq*4+1][r] = v.y;
            b_t[kq*4+2][r] = v.z; b_t[kq*4+3][r] = v.w;
        }
        __syncthreads();
#pragma unroll
        for (int kk = 0; kk < 16; ++kk) {
            float4 a0 = *(const float4*)&a_t[kk][ty * 8];
            float4 a1 = *(const float4*)&a_t[kk][ty * 8 + 4];
            float4 b0 = *(const float4*)&b_t[kk][tx * 4];
            float am[8] = {a0.x,a0.y,a0.z,a0.w,a1.x,a1.y,a1.z,a1.w};
            float bn[4] = {b0.x,b0.y,b0.z,b0.w};
#pragma unroll
            for (int i = 0; i < 8; ++i)
#pragma unroll
                for (int j = 0; j < 4; ++j)
                    acc[i][j] = fmaf(am[i], bn[j], acc[i][j]);
        }
        __syncthreads();
    }
    const float scale = 0.17677669529663687f;   // 32^-0.5
#pragma unroll
    for (int i = 0; i < 8; ++i) {
        int m = m0 + ty * 8 + i;
        int nw = m >> 6, ii = m & 63;
#pragma unroll
        for (int j = 0; j < 4; ++j) {
            int c = n0 + tx * 4 + j;
            float v = acc[i][j] + bias[c];
            int s = c >> 8;
            int rem = c & 255;
            int h = rem >> 5, d = rem & 31;
            size_t off = ((size_t)((nw * 8 + h) * 64 + ii)) * 32 + d;
            if (s == 0)      qb[off] = v * scale;
            else if (s == 1) kb[off] = v;
            else             vb[off] = v;
        }
    }
}

// ---------------------------------------------------------------------------
// Per-(window,head) attention. Block=256 threads, one block per (n,h).
// Thread role: row = tid>>2 (i or j depending on phase), jc = tid&3.
// j lane mapping: j = jj*4 + jc (interleaved, avoids LDS bank conflicts).
// ---------------------------------------------------------------------------
__global__ __launch_bounds__(256) void k_attn(
    const float* __restrict__ qb, const float* __restrict__ kb, const float* __restrict__ vb,
    const float* __restrict__ nco,
    const float* __restrict__ qxt, const float* __restrict__ kxt, const float* __restrict__ vxt,
    const float* __restrict__ qrt, const float* __restrict__ krt, const float* __restrict__ vrt,
    float* __restrict__ aout)
{
    __shared__ float q_s[64][36];
    __shared__ float kv_s[64][36];       // k, later v
    __shared__ float dbuf[64 * 121];     // dk/dq rows, later "at" scatter bins
    __shared__ float cw_s[64][8];        // [0..2]=xyz*4, [4..6]=rgb*8

    const int tid = threadIdx.x;
    const int n = blockIdx.x >> 3;
    const int h = blockIdx.x & 7;
    const int row = tid >> 2;
    const int jc = tid & 3;

    const size_t qkv_base = (size_t)((n * 8 + h) * 64) * 32;
    const float* qg = qb + qkv_base;
    const float* kg = kb + qkv_base;
#pragma unroll
    for (int l = 0; l < 2; ++l) {
        int e = (tid + l * 256) * 4;     // 0..2044
        int r = e >> 5, d = e & 31;
        *(float4*)&q_s[r][d]  = *(const float4*)(qg + e);
        *(float4*)&kv_s[r][d] = *(const float4*)(kg + e);
    }
    {
        int e = tid;
        if (e < 384) {
            int i = e / 6, c = e % 6;
            cw_s[i][c < 3 ? c : c + 1] = nco[(size_t)(n * 64 + i) * 6 + c] * (c < 3 ? 4.0f : 8.0f);
        }
        e = tid + 256;
        if (e < 384) {
            int i = e / 6, c = e % 6;
            cw_s[i][c < 3 ? c : c + 1] = nco[(size_t)(n * 64 + i) * 6 + c] * (c < 3 ? 4.0f : 8.0f);
        }
    }
    __syncthreads();

    float rr[32];
    float lg[16];

    auto loadRow = [&](const float (*src)[36]) {
#pragma unroll
        for (int d = 0; d < 32; d += 4) {
            float4 v = *(const float4*)&src[row][d];
            rr[d] = v.x; rr[d+1] = v.y; rr[d+2] = v.z; rr[d+3] = v.w;
        }
    };
    // dbuf[row][r] = rr . table_row(r), r = ri*4+jc
    auto tableGemm = [&](const float* tb, int R4, int stride) {
#pragma unroll 2
        for (int ri = 0; ri < R4; ++ri) {
            int r = ri * 4 + jc;
            const float* trow = tb + r * 256;
            float s = 0.f;
#pragma unroll
            for (int d = 0; d < 32; d += 4) {
                float4 tv = *(const float4*)(trow + d);
                s = fmaf(rr[d],   tv.x, s); s = fmaf(rr[d+1], tv.y, s);
                s = fmaf(rr[d+2], tv.z, s); s = fmaf(rr[d+3], tv.w, s);
            }
            dbuf[row * stride + r] = s;
        }
    };
    auto clampi = [](int x, int hi) { return x < 0 ? 0 : (x > hi ? hi : x); };

    // gather bias_k: lg[jj] += dbuf[j*stride + c*T + t(i,j,c)]
    auto gatherK = [&](int cOff, int offs, int hi, int T, int stride) {
        float4 ci = *(const float4*)&cw_s[row][cOff];
#pragma unroll
        for (int jj = 0; jj < 16; ++jj) {
            int j = jj * 4 + jc;
            float4 cj = *(const float4*)&cw_s[j][cOff];
            int t0 = clampi((int)floorf(ci.x - cj.x) + offs, hi);
            int t1 = clampi((int)floorf(ci.y - cj.y) + offs, hi);
            int t2 = clampi((int)floorf(ci.z - cj.z) + offs, hi);
            const float* db = dbuf + j * stride;
            lg[jj] += db[t0] + db[T + t1] + db[2 * T + t2];
        }
    };
    // gather bias_q: lg[jj] += dbuf[i*stride + c*T + t(i,j,c)]
    auto gatherQ = [&](int cOff, int offs, int hi, int T, int stride) {
        float4 ci = *(const float4*)&cw_s[row][cOff];
        const float* db = dbuf + row * stride;
#pragma unroll
        for (int jj = 0; jj < 16; ++jj) {
            int j = jj * 4 + jc;
            float4 cj = *(const float4*)&cw_s[j][cOff];
            int t0 = clampi((int)floorf(ci.x - cj.x) + offs, hi);
            int t1 = clampi((int)floorf(ci.y - cj.y) + offs, hi);
            int t2 = clampi((int)floorf(ci.z - cj.z) + offs, hi);
            lg[jj] += db[t0] + db[T + t1] + db[2 * T + t2];
        }
    };

    // ---- QK ----
    loadRow(q_s);
#pragma unroll
    for (int jj = 0; jj < 16; ++jj) {
        int j = jj * 4 + jc;
        float s = 0.f;
#pragma unroll
        for (int d = 0; d < 32; d += 4) {
            float4 kv = *(const float4*)&kv_s[j][d];
            s = fmaf(rr[d],   kv.x, s); s = fmaf(rr[d+1], kv.y, s);
            s = fmaf(rr[d+2], kv.z, s); s = fmaf(rr[d+3], kv.w, s);
        }
        lg[jj] = s;
    }

    // ---- dk xyz / rgb ----
    loadRow(kv_s);
    tableGemm(kxt + h * 32, 30, 121);
    __syncthreads();
    gatherK(0, 20, 39, 40, 121);
    __syncthreads();
    tableGemm(krt + h * 32, 24, 97);
    __syncthreads();
    gatherK(4, 16, 31, 32, 97);
    __syncthreads();

    // ---- dq xyz / rgb ----
    loadRow(q_s);
    tableGemm(qxt + h * 32, 30, 121);
    __syncthreads();
    {   // load v into kv_s (k no longer needed) alongside gather_q xyz
        const float* vg = vb + qkv_base;
#pragma unroll
        for (int l = 0; l < 2; ++l) {
            int e = (tid + l * 256) * 4;
            *(float4*)&kv_s[e >> 5][e & 31] = *(const float4*)(vg + e);
        }
        gatherQ(0, 20, 39, 40, 121);
    }
    __syncthreads();
    tableGemm(qrt + h * 32, 24, 97);
    __syncthreads();
    gatherQ(4, 16, 31, 32, 97);

    // ---- softmax over full row (4 lanes x 16) ----
    float mx = lg[0];
#pragma unroll
    for (int jj = 1; jj < 16; ++jj) mx = fmaxf(mx, lg[jj]);
    mx = fmaxf(mx, __shfl_xor(mx, 1));
    mx = fmaxf(mx, __shfl_xor(mx, 2));
    float sum = 0.f;
#pragma unroll
    for (int jj = 0; jj < 16; ++jj) { lg[jj] = __expf(lg[jj] - mx); sum += lg[jj]; }
    sum += __shfl_xor(sum, 1);
    sum += __shfl_xor(sum, 2);
    float inv = 1.f / sum;
#pragma unroll
    for (int jj = 0; jj < 16; ++jj) lg[jj] *= inv;

    float oa[32];
#pragma unroll
    for (int d = 0; d < 32; ++d) oa[d] = 0.f;

    // ---- attn @ v ----
#pragma unroll
    for (int jj = 0; jj < 16; ++jj) {
        int j = jj * 4 + jc;
        float a = lg[jj];
#pragma unroll
        for (int d = 0; d < 32; d += 4) {
            float4 vv = *(const float4*)&kv_s[j][d];
            oa[d]   = fmaf(a, vv.x, oa[d]);   oa[d+1] = fmaf(a, vv.y, oa[d+1]);
            oa[d+2] = fmaf(a, vv.z, oa[d+2]); oa[d+3] = fmaf(a, vv.w, oa[d+3]);
        }
    }

    auto scatter = [&](int cOff, int offs, int hi, int T, int stride) {
        float4 ci = *(const float4*)&cw_s[row][cOff];
        float* db = dbuf + row * stride;
#pragma unroll
        for (int jj = 0; jj < 16; ++jj) {
            int j = jj * 4 + jc;
            float4 cj = *(const float4*)&cw_s[j][cOff];
            int t0 = clampi((int)floorf(ci.x - cj.x) + offs, hi);
            int t1 = clampi((int)floorf(ci.y - cj.y) + offs, hi);
            int t2 = clampi((int)floorf(ci.z - cj.z) + offs, hi);
            float a = lg[jj];
            atomicAdd(&db[t0], a);
            atomicAdd(&db[T + t1], a);
            atomicAdd(&db[2 * T + t2], a);
        }
    };
    auto atGemm = [&](const float* tb, int R4, int stride) {
#pragma unroll 2
        for (int ri = 0; ri < R4; ++ri) {
            int r = ri * 4 + jc;
            float a = dbuf[row * stride + r];
            const float* trow = tb + r * 256;
#pragma unroll
            for (int d = 0; d < 32; d += 4) {
                float4 tv = *(const float4*)(trow + d);
                oa[d]   = fmaf(a, tv.x, oa[d]);   oa[d+1] = fmaf(a, tv.y, oa[d+1]);
                oa[d+2] = fmaf(a, tv.z, oa[d+2]); oa[d+3] = fmaf(a, tv.w, oa[d+3]);
            }
        }
    };

    // ---- value bias xyz ----
    __syncthreads();                              // everyone done reading dbuf
    for (int e = tid; e < 64 * 121; e += 256) dbuf[e] = 0.f;
    __syncthreads();
    scatter(0, 20, 39, 40, 121);
    __syncthreads();
    atGemm(vxt + h * 32, 30, 121);
    // ---- value bias rgb ----
    __syncthreads();
    for (int e = tid; e < 64 * 97; e += 256) dbuf[e] = 0.f;
    __syncthreads();
    scatter(4, 16, 31, 32, 97);
    __syncthreads();
    atGemm(vrt + h * 32, 24, 97);

    // ---- reduce 4 lanes, write ----
#pragma unroll
    for (int d = 0; d < 32; ++d) {
        oa[d] += __shfl_xor(oa[d], 1);
        oa[d] += __shfl_xor(oa[d], 2);
    }
    float* op = aout + (size_t)(n * 64 + row) * 256 + h * 32 + jc * 8;
    float4 w0, w1;
    if (jc == 0)      { w0 = make_float4(oa[0],oa[1],oa[2],oa[3]);     w1 = make_float4(oa[4],oa[5],oa[6],oa[7]); }
    else if (jc == 1) { w0 = make_float4(oa[8],oa[9],oa[10],oa[11]);   w1 = make_float4(oa[12],oa[13],oa[14],oa[15]); }
    else if (jc == 2) { w0 = make_float4(oa[16],oa[17],oa[18],oa[19]); w1 = make_float4(oa[20],oa[21],oa[22],oa[23]); }
    else              { w0 = make_float4(oa[24],oa[25],oa[26],oa[27]); w1 = make_float4(oa[28],oa[29],oa[30],oa[31]); }
    *(float4*)op = w0;
    *(float4*)(op + 4) = w1;
}

// ---------------------------------------------------------------------------
// Proj GEMM: out[m,n] = ao[m,:] . proj_w[n,:] + proj_b[n]. BM=BN=64 BK=32.
// ---------------------------------------------------------------------------
__global__ __launch_bounds__(256) void k_proj(
    const float* __restrict__ A, const float* __restrict__ Wt,
    const float* __restrict__ bias, float* __restrict__ out)
{
    __shared__ float a_t[32][68];
    __shared__ float b_t[32][68];
    const int tid = threadIdx.x;
    const int m0 = blockIdx.y * 64;
    const int n0 = blockIdx.x * 64;
    const int tx = tid & 15;
    const int ty = tid >> 4;
    float acc[4][4];
#pragma unroll
    for (int i = 0; i < 4; ++i)
#pragma unroll
        for (int j = 0; j < 4; ++j) acc[i][j] = 0.f;

    for (int k0 = 0; k0 < 256; k0 += 32) {
#pragma unroll
        for (int l = 0; l < 2; ++l) {
            int e = tid + l * 256;   // 0..511
            int r = e >> 3;          // 0..63
            int kq = e & 7;
            float4 v = *(const float4*)(A + (size_t)(m0 + r) * 256 + k0 + kq * 4);
            a_t[kq*4+0][r] = v.x; a_t[kq*4+1][r] = v.y;
            a_t[kq*4+2][r] = v.z; a_t[kq*4+3][r] = v.w;
            float4 w = *(const float4*)(Wt + (size_t)(n0 + r) * 256 + k0 + kq * 4);
            b_t[kq*4+0][r] = w.x; b_t[kq*4+1][r] = w.y;
            b_t[kq*4+2][r] = w.z; b_t[kq*4+3][r] = w.w;
        }
        __syncthreads();
#pragma unroll
        for (int kk = 0; kk < 32; ++kk) {
            float4 a4 = *(const float4*)&a_t[kk][ty * 4];
            float4 b4 = *(const float4*)&b_t[kk][tx * 4];
            float am[4] = {a4.x,a4.y,a4.z,a4.w};
            float bn[4] = {b4.x,b4.y,b4.z,b4.w};
#pragma unroll
            for (int i = 0; i < 4; ++i)
#pragma unroll
                for (int j = 0; j < 4; ++j)
                    acc[i][j] = fmaf(am[i], bn[j], acc[i][j]);
        }
        __syncthreads();
    }
    int nn = n0 + tx * 4;
    float4 bb = *(const float4*)(bias + nn);
#pragma unroll
    for (int i = 0; i < 4; ++i) {
        int m = m0 + ty * 4 + i;
        float4 o;
        o.x = acc[i][0] + bb.x; o.y = acc[i][1] + bb.y;
        o.z = acc[i][2] + bb.z; o.w = acc[i][3] + bb.w;
        *(float4*)(out + (size_t)m * 256 + nn) = o;
    }
}

extern "C" void kernel_launch(void* const* d_in, const int* in_sizes, int n_in,
                              void* d_out, int out_size, void* d_ws, size_t ws_size,
                              hipStream_t stream)
{
    const float* feats = (const float*)d_in[0];
    const float* nco   = (const float*)d_in[1];
    const float* qkvw  = (const float*)d_in[2];
    const float* qkvb  = (const float*)d_in[3];
    const float* qxt   = (const float*)d_in[4];
    const float* kxt   = (const float*)d_in[5];
    const float* vxt   = (const float*)d_in[6];
    const float* qrt   = (const float*)d_in[7];
    const float* krt   = (const float*)d_in[8];
    const float* vrt   = (const float*)d_in[9];
    const float* pw    = (const float*)d_in[10];
    const float* pb    = (const float*)d_in[11];
    float* out = (float*)d_out;

    float* qb = (float*)d_ws;                 // [128][8][64][32]
    float* kb = qb + (size_t)8192 * 256;
    float* vb = kb + (size_t)8192 * 256;
    float* ao = vb + (size_t)8192 * 256;      // [8192][256]

    k_qkv<<<dim3(12, 64), 256, 0, stream>>>(feats, qkvw, qkvb, qb, kb, vb);
    k_attn<<<dim3(1024), 256, 0, stream>>>(qb, kb, vb, nco, qxt, kxt, vxt, qrt, krt, vrt, ao);
    k_proj<<<dim3(4, 128), 256, 0, stream>>>(ao, pw, pb, out);
}

// Round 2
// 305.780 us; speedup vs baseline: 3.1107x; 3.1107x over previous
//
#include <hip/hip_runtime.h>

// DIM=256 H=8 HD=32 W=64 N=8192 nw=128
// xyz: T=40, off=20, hi=39, R=120 (pad 128) ; rgb: T=32, off=16, hi=31, R=96
// table element ((c*T+t)*8+h)*32+d == r*256 + h*32 + d, r=c*T+t

typedef __attribute__((ext_vector_type(8))) short short8;
typedef __attribute__((ext_vector_type(4))) float f32x4;

__device__ __forceinline__ unsigned short f2bf(float f) {
    union { float f; unsigned int u; } v; v.f = f;
    unsigned int r = v.u + 0x7FFFu + ((v.u >> 16) & 1u);
    return (unsigned short)(r >> 16);
}

// ---------------------------------------------------------------------------
// QKV GEMM (fp32 VALU): qkv = feats @ qkv_w^T + b; outputs q/k/v as bf16 in
// [nw][H][W][HD] layout, q pre-scaled by 32^-0.5.
// ---------------------------------------------------------------------------
__global__ __launch_bounds__(256) void k_qkv(
    const float* __restrict__ A, const float* __restrict__ Wt,
    const float* __restrict__ bias,
    ushort* __restrict__ qb, ushort* __restrict__ kb, ushort* __restrict__ vb)
{
    __shared__ float a_t[16][132];
    __shared__ float b_t[16][68];
    const int tid = threadIdx.x;
    const int m0 = blockIdx.y * 128;
    const int n0 = blockIdx.x * 64;
    const int tx = tid & 15;
    const int ty = tid >> 4;
    float acc[8][4];
#pragma unroll
    for (int i = 0; i < 8; ++i)
#pragma unroll
        for (int j = 0; j < 4; ++j) acc[i][j] = 0.f;

    for (int k0 = 0; k0 < 256; k0 += 16) {
#pragma unroll
        for (int l = 0; l < 2; ++l) {
            int e = tid + l * 256;
            int r = e >> 2, kq = e & 3;
            float4 v = *(const float4*)(A + (size_t)(m0 + r) * 256 + k0 + kq * 4);
            a_t[kq*4+0][r] = v.x; a_t[kq*4+1][r] = v.y;
            a_t[kq*4+2][r] = v.z; a_t[kq*4+3][r] = v.w;
        }
        {
            int r = tid >> 2, kq = tid & 3;
            float4 v = *(const float4*)(Wt + (size_t)(n0 + r) * 256 + k0 + kq * 4);
            b_t[kq*4+0][r] = v.x; b_t[kq*4+1][r] = v.y;
            b_t[kq*4+2][r] = v.z; b_t[kq*4+3][r] = v.w;
        }
        __syncthreads();
#pragma unroll
        for (int kk = 0; kk < 16; ++kk) {
            float4 a0 = *(const float4*)&a_t[kk][ty * 8];
            float4 a1 = *(const float4*)&a_t[kk][ty * 8 + 4];
            float4 b0 = *(const float4*)&b_t[kk][tx * 4];
            float am[8] = {a0.x,a0.y,a0.z,a0.w,a1.x,a1.y,a1.z,a1.w};
            float bn[4] = {b0.x,b0.y,b0.z,b0.w};
#pragma unroll
            for (int i = 0; i < 8; ++i)
#pragma unroll
                for (int j = 0; j < 4; ++j)
                    acc[i][j] = fmaf(am[i], bn[j], acc[i][j]);
        }
        __syncthreads();
    }
    const float scale = 0.17677669529663687f;
#pragma unroll
    for (int i = 0; i < 8; ++i) {
        int m = m0 + ty * 8 + i;
        int nw = m >> 6, ii = m & 63;
#pragma unroll
        for (int j = 0; j < 4; ++j) {
            int c = n0 + tx * 4 + j;
            float v = acc[i][j] + bias[c];
            int s = c >> 8;
            int rem = c & 255;
            int hh = rem >> 5, d = rem & 31;
            size_t off = ((size_t)((nw * 8 + hh) * 64 + ii)) * 32 + d;
            if (s == 0)      qb[off] = f2bf(v * scale);
            else if (s == 1) kb[off] = f2bf(v);
            else             vb[off] = f2bf(v);
        }
    }
}

// ---------------------------------------------------------------------------
// MFMA attention per (window, head). 256 threads = 4 waves; wave w owns
// M-tile w (16 rows). mfma_f32_16x16x32_bf16 layouts (HW-verified):
//   A/B frag: [outer = lane&15][k = quad*8 + j]  (8 bf16 = b128 read)
//   C/D:      col = lane&15, row = quad*4 + reg
// ---------------------------------------------------------------------------
#define DBS 130

__global__ __launch_bounds__(256, 2) void k_attn(
    const ushort* __restrict__ qb, const ushort* __restrict__ kb, const ushort* __restrict__ vb,
    const float* __restrict__ nco,
    const float* __restrict__ qxt, const float* __restrict__ kxt, const float* __restrict__ vxt,
    const float* __restrict__ qrt, const float* __restrict__ krt, const float* __restrict__ vrt,
    float* __restrict__ aout)
{
    __shared__ __align__(16) ushort q_s[64*40];     // bf16 q rows, stride 40
    __shared__ __align__(16) ushort kvu[64*40];     // k rows; later v_t[32][72]
    __shared__ __align__(16) ushort tblu[128*40];   // tbl[r][40] ; later vtbl_t[32][136]
    __shared__ __align__(16) float  dbuf[64*DBS];   // dq/dk rows; later at-bins
    __shared__ __align__(16) ushort attn_s[64*72];  // bf16 attn, stride 72
    __shared__ float4 cw_x[64];
    __shared__ float4 cw_r[64];

    const int tid = threadIdx.x;
    const int n = blockIdx.x >> 3;
    const int h = blockIdx.x & 7;
    const int w = tid >> 6;
    const int l4 = tid & 15;
    const int quad = (tid >> 4) & 3;

    ushort* k_s = kvu;
    ushort* v_t = kvu;            // [32][72], staged after k is dead
    ushort* tbl_s = tblu;
    ushort* vtbl_s = tblu;        // [32][136]

    const size_t base = (size_t)((n * 8 + h) * 64) * 32;

    // ---- stage q, k, coords, tbl(kx) ----
    {
        int row = tid >> 2, part = tid & 3;
        *(uint4*)&q_s[row*40 + part*8] = *(const uint4*)(qb + base + tid*8);
        *(uint4*)&k_s[row*40 + part*8] = *(const uint4*)(kb + base + tid*8);
    }
    if (tid < 64) {
        const float* cp = nco + (size_t)(n*64 + tid) * 6;
        cw_x[tid] = make_float4(cp[0]*4.f, cp[1]*4.f, cp[2]*4.f, 0.f);
        cw_r[tid] = make_float4(cp[3]*8.f, cp[4]*8.f, cp[5]*8.f, 0.f);
    }

    auto stageTbl = [&](const float* tb, int R, int Rpad) {
        int r = tid >> 1, half = tid & 1;
        if (r < R) {
            const float* src = tb + (size_t)r * 256 + half * 16;
            ushort* dst = &tbl_s[r*40 + half*16];
#pragma unroll
            for (int ii = 0; ii < 16; ii += 4) {
                float4 vv = *(const float4*)(src + ii);
                dst[ii+0] = f2bf(vv.x); dst[ii+1] = f2bf(vv.y);
                dst[ii+2] = f2bf(vv.z); dst[ii+3] = f2bf(vv.w);
            }
        }
        for (int e = tid; e < (Rpad - R) * 40; e += 256) tbl_s[R*40 + e] = 0;
    };
    auto stageVtbl = [&](const float* tb, int R) {
        int r = tid >> 1, half = tid & 1;
        if (r < R) {
            const float* src = tb + (size_t)r * 256 + half * 16;
#pragma unroll
            for (int ii = 0; ii < 16; ++ii)
                vtbl_s[(half*16 + ii)*136 + r] = f2bf(src[ii]);
        }
        int span = 128 - R;
        for (int e = tid; e < 32 * span; e += 256) {
            int d = e / span, rr = e - d * span;
            vtbl_s[d*136 + R + rr] = 0;
        }
    };
    auto stageVt = [&]() {
        int j = tid >> 2, d0 = (tid & 3) * 8;
        uint4 pk = *(const uint4*)(vb + base + tid*8);
        const ushort* u = (const ushort*)&pk;
#pragma unroll
        for (int ii = 0; ii < 8; ++ii) v_t[(d0 + ii)*72 + j] = u[ii];
    };

    // dX[outer][r] = X[outer,:] . tbl[r,:]  -> dbuf rows
    auto tgemm = [&](const ushort* a_s, int NT) {
        short8 af = *(const short8*)&a_s[(w*16 + l4)*40 + quad*8];
        for (int tt = 0; tt < NT; ++tt) {
            short8 bf = *(const short8*)&tbl_s[(tt*16 + l4)*40 + quad*8];
            f32x4 acc = {0.f, 0.f, 0.f, 0.f};
            acc = __builtin_amdgcn_mfma_f32_16x16x32_bf16(af, bf, acc, 0, 0, 0);
            int col = tt*16 + l4;
            int rb = w*16 + quad*4;
            dbuf[(rb+0)*DBS + col] = acc[0];
            dbuf[(rb+1)*DBS + col] = acc[1];
            dbuf[(rb+2)*DBS + col] = acc[2];
            dbuf[(rb+3)*DBS + col] = acc[3];
        }
    };

    float lg[4][4];   // logits: row i = w*16+quad*4+reg, col j = tt*16+l4

    auto gather = [&](const float4* cwp, int T, int offs, int hi, bool useJ) {
#pragma unroll
        for (int reg = 0; reg < 4; ++reg) {
            int i = w*16 + quad*4 + reg;
            float4 ci = cwp[i];
#pragma unroll
            for (int tt = 0; tt < 4; ++tt) {
                int j = tt*16 + l4;
                float4 cj = cwp[j];
                int a0 = min(max((int)floorf(ci.x - cj.x) + offs, 0), hi);
                int a1 = min(max((int)floorf(ci.y - cj.y) + offs, 0), hi);
                int a2 = min(max((int)floorf(ci.z - cj.z) + offs, 0), hi);
                const float* db = &dbuf[(useJ ? j : i) * DBS];
                lg[tt][reg] += db[a0] + db[T + a1] + db[2*T + a2];
            }
        }
    };
    auto scatter = [&](const float4* cwp, int T, int offs, int hi) {
#pragma unroll
        for (int reg = 0; reg < 4; ++reg) {
            int i = w*16 + quad*4 + reg;
            float4 ci = cwp[i];
            float* bi = &dbuf[i * DBS];
#pragma unroll
            for (int tt = 0; tt < 4; ++tt) {
                int j = tt*16 + l4;
                float4 cj = cwp[j];
                int a0 = min(max((int)floorf(ci.x - cj.x) + offs, 0), hi);
                int a1 = min(max((int)floorf(ci.y - cj.y) + offs, 0), hi);
                int a2 = min(max((int)floorf(ci.z - cj.z) + offs, 0), hi);
                float a = lg[tt][reg];
                atomicAdd(bi + a0, a);
                atomicAdd(bi + T + a1, a);
                atomicAdd(bi + 2*T + a2, a);
            }
        }
    };
    auto zeroBins = [&]() {
        float4 z = {0.f, 0.f, 0.f, 0.f};
        for (int e = tid * 4; e < 64 * DBS; e += 1024) *(float4*)&dbuf[e] = z;
    };

    stageTbl(kxt + h*32, 120, 128);
    __syncthreads();

    // ---- QK logits + dk_xyz ----
    {
        short8 aq = *(const short8*)&q_s[(w*16 + l4)*40 + quad*8];
#pragma unroll
        for (int tt = 0; tt < 4; ++tt) {
            short8 bk = *(const short8*)&k_s[(tt*16 + l4)*40 + quad*8];
            f32x4 r = {0.f, 0.f, 0.f, 0.f};
            r = __builtin_amdgcn_mfma_f32_16x16x32_bf16(aq, bk, r, 0, 0, 0);
            lg[tt][0] = r[0]; lg[tt][1] = r[1]; lg[tt][2] = r[2]; lg[tt][3] = r[3];
        }
    }
    tgemm(k_s, 8);                       // dk_xyz
    __syncthreads();
    gather(cw_x, 40, 20, 39, true);      // bias_k xyz
    stageTbl(krt + h*32, 96, 96);
    __syncthreads();
    tgemm(k_s, 6);                       // dk_rgb
    __syncthreads();
    gather(cw_r, 32, 16, 31, true);      // bias_k rgb
    stageTbl(qxt + h*32, 120, 128);
    __syncthreads();
    tgemm(q_s, 8);                       // dq_xyz
    __syncthreads();
    gather(cw_x, 40, 20, 39, false);     // bias_q xyz
    stageTbl(qrt + h*32, 96, 96);
    __syncthreads();
    tgemm(q_s, 6);                       // dq_rgb
    __syncthreads();
    gather(cw_r, 32, 16, 31, false);     // bias_q rgb
    stageVtbl(vxt + h*32, 120);          // tbl region free now
    stageVt();                           // k region free now
    __syncthreads();

    // ---- softmax (rows split over tt-local + 16 l4-lanes) ----
#pragma unroll
    for (int reg = 0; reg < 4; ++reg) {
        float m = fmaxf(fmaxf(lg[0][reg], lg[1][reg]), fmaxf(lg[2][reg], lg[3][reg]));
        m = fmaxf(m, __shfl_xor(m, 1));
        m = fmaxf(m, __shfl_xor(m, 2));
        m = fmaxf(m, __shfl_xor(m, 4));
        m = fmaxf(m, __shfl_xor(m, 8));
        float s = 0.f;
#pragma unroll
        for (int tt = 0; tt < 4; ++tt) { lg[tt][reg] = __expf(lg[tt][reg] - m); s += lg[tt][reg]; }
        s += __shfl_xor(s, 1); s += __shfl_xor(s, 2);
        s += __shfl_xor(s, 4); s += __shfl_xor(s, 8);
        float inv = 1.f / s;
#pragma unroll
        for (int tt = 0; tt < 4; ++tt) lg[tt][reg] *= inv;
    }
#pragma unroll
    for (int tt = 0; tt < 4; ++tt)
#pragma unroll
        for (int reg = 0; reg < 4; ++reg)
            attn_s[(w*16 + quad*4 + reg)*72 + tt*16 + l4] = f2bf(lg[tt][reg]);
    zeroBins();
    __syncthreads();

    // ---- scatter xyz bins + AV ----
    scatter(cw_x, 40, 20, 39);
    f32x4 acc0 = {0.f, 0.f, 0.f, 0.f}, acc1 = {0.f, 0.f, 0.f, 0.f};
#pragma unroll
    for (int s = 0; s < 2; ++s) {
        short8 af = *(const short8*)&attn_s[(w*16 + l4)*72 + s*32 + quad*8];
        short8 b0 = *(const short8*)&v_t[l4*72 + s*32 + quad*8];
        short8 b1 = *(const short8*)&v_t[(16 + l4)*72 + s*32 + quad*8];
        acc0 = __builtin_amdgcn_mfma_f32_16x16x32_bf16(af, b0, acc0, 0, 0, 0);
        acc1 = __builtin_amdgcn_mfma_f32_16x16x32_bf16(af, b1, acc1, 0, 0, 0);
    }
    __syncthreads();

    auto atgemm = [&]() {
#pragma unroll
        for (int s = 0; s < 4; ++s) {
            const float* ap = &dbuf[(w*16 + l4)*DBS + s*32 + quad*8];
            short8 af;
#pragma unroll
            for (int ii = 0; ii < 8; ++ii) af[ii] = (short)f2bf(ap[ii]);
            short8 b0 = *(const short8*)&vtbl_s[l4*136 + s*32 + quad*8];
            short8 b1 = *(const short8*)&vtbl_s[(16 + l4)*136 + s*32 + quad*8];
            acc0 = __builtin_amdgcn_mfma_f32_16x16x32_bf16(af, b0, acc0, 0, 0, 0);
            acc1 = __builtin_amdgcn_mfma_f32_16x16x32_bf16(af, b1, acc1, 0, 0, 0);
        }
    };
    atgemm();                            // value-bias xyz
    __syncthreads();
    zeroBins();
    stageVtbl(vrt + h*32, 96);
    __syncthreads();
    scatter(cw_r, 32, 16, 31);
    __syncthreads();
    atgemm();                            // value-bias rgb

    // ---- epilogue: out[i][h*32 + d] ----
    {
        float* op = aout + (size_t)(n*64 + w*16 + quad*4) * 256 + h*32;
#pragma unroll
        for (int reg = 0; reg < 4; ++reg) {
            op[reg*256 + l4] = acc0[reg];
            op[reg*256 + 16 + l4] = acc1[reg];
        }
    }
}

// ---------------------------------------------------------------------------
// Proj GEMM (fp32 VALU): out = ao @ proj_w^T + proj_b
// ---------------------------------------------------------------------------
__global__ __launch_bounds__(256) void k_proj(
    const float* __restrict__ A, const float* __restrict__ Wt,
    const float* __restrict__ bias, float* __restrict__ out)
{
    __shared__ float a_t[32][68];
    __shared__ float b_t[32][68];
    const int tid = threadIdx.x;
    const int m0 = blockIdx.y * 64;
    const int n0 = blockIdx.x * 64;
    const int tx = tid & 15;
    const int ty = tid >> 4;
    float acc[4][4];
#pragma unroll
    for (int i = 0; i < 4; ++i)
#pragma unroll
        for (int j = 0; j < 4; ++j) acc[i][j] = 0.f;

    for (int k0 = 0; k0 < 256; k0 += 32) {
#pragma unroll
        for (int l = 0; l < 2; ++l) {
            int e = tid + l * 256;
            int r = e >> 3, kq = e & 7;
            float4 v = *(const float4*)(A + (size_t)(m0 + r) * 256 + k0 + kq * 4);
            a_t[kq*4+0][r] = v.x; a_t[kq*4+1][r] = v.y;
            a_t[kq*4+2][r] = v.z; a_t[kq*4+3][r] = v.w;
            float4 ww = *(const float4*)(Wt + (size_t)(n0 + r) * 256 + k0 + kq * 4);
            b_t[kq*4+0][r] = ww.x; b_t[kq*4+1][r] = ww.y;
            b_t[kq*4+2][r] = ww.z; b_t[kq*4+3][r] = ww.w;
        }
        __syncthreads();
#pragma unroll
        for (int kk = 0; kk < 32; ++kk) {
            float4 a4 = *(const float4*)&a_t[kk][ty * 4];
            float4 b4 = *(const float4*)&b_t[kk][tx * 4];
            float am[4] = {a4.x,a4.y,a4.z,a4.w};
            float bn[4] = {b4.x,b4.y,b4.z,b4.w};
#pragma unroll
            for (int i = 0; i < 4; ++i)
#pragma unroll
                for (int j = 0; j < 4; ++j)
                    acc[i][j] = fmaf(am[i], bn[j], acc[i][j]);
        }
        __syncthreads();
    }
    int nn = n0 + tx * 4;
    float4 bb = *(const float4*)(bias + nn);
#pragma unroll
    for (int i = 0; i < 4; ++i) {
        int m = m0 + ty * 4 + i;
        float4 o;
        o.x = acc[i][0] + bb.x; o.y = acc[i][1] + bb.y;
        o.z = acc[i][2] + bb.z; o.w = acc[i][3] + bb.w;
        *(float4*)(out + (size_t)m * 256 + nn) = o;
    }
}

extern "C" void kernel_launch(void* const* d_in, const int* in_sizes, int n_in,
                              void* d_out, int out_size, void* d_ws, size_t ws_size,
                              hipStream_t stream)
{
    const float* feats = (const float*)d_in[0];
    const float* nco   = (const float*)d_in[1];
    const float* qkvw  = (const float*)d_in[2];
    const float* qkvb  = (const float*)d_in[3];
    const float* qxt   = (const float*)d_in[4];
    const float* kxt   = (const float*)d_in[5];
    const float* vxt   = (const float*)d_in[6];
    const float* qrt   = (const float*)d_in[7];
    const float* krt   = (const float*)d_in[8];
    const float* vrt   = (const float*)d_in[9];
    const float* pw    = (const float*)d_in[10];
    const float* pb    = (const float*)d_in[11];
    float* out = (float*)d_out;

    ushort* qb = (ushort*)d_ws;                    // [128][8][64][32] bf16
    ushort* kb = qb + (size_t)8192 * 256;
    ushort* vb = kb + (size_t)8192 * 256;
    float*  ao = (float*)(vb + (size_t)8192 * 256); // [8192][256] fp32

    k_qkv<<<dim3(12, 64), 256, 0, stream>>>(feats, qkvw, qkvb, qb, kb, vb);
    k_attn<<<dim3(1024), 256, 0, stream>>>(qb, kb, vb, nco, qxt, kxt, vxt, qrt, krt, vrt, ao);
    k_proj<<<dim3(4, 128), 256, 0, stream>>>(ao, pw, pb, out);
}